// Round 15
// baseline (84.905 us; speedup 1.0000x reference)
//
#include <hip/hip_runtime.h>

// Problem constants: B=256, T=256, H=768, S=130
#define BB 256
#define TT 256
#define HH 768
#define SS 130
#define NPH 6                    // K phases of 128
#define SROWS 144                // 9 n-tiles x 16 rows per B slice
#define SLU (SROWS * 64)         // uints per wsT2 phase slice = 9216 (36864 B)
#define MSP 10                   // merge: s-rows per block (130 = 13*10)

typedef __attribute__((ext_vector_type(8))) __bf16 bf16x8;
typedef __attribute__((ext_vector_type(4))) float f32x4;

__device__ __forceinline__ unsigned f2bf(float f) {
    unsigned x = __builtin_bit_cast(unsigned, f);
    x = (x + 0x7FFFu + ((x >> 16) & 1u)) >> 16;
    return x & 0xFFFFu;
}
__device__ __forceinline__ float bf2f(unsigned short u) {
    return __builtin_bit_cast(float, (unsigned)u << 16);
}

// ---- prep: [0..53] W -> wsT2 [6][144 s][128 k bf16], 16B-slot j at j^(s&15);
//            [54..309] seg -> bounds {start,count} ----
__global__ __launch_bounds__(256)
void prep_kernel(const float* __restrict__ W, unsigned* __restrict__ wsT2,
                 const int* __restrict__ seg, int2* __restrict__ bounds)
{
    __shared__ __align__(16) char pm[128 * 17 * 4];   // 8704 B
    const int tid = threadIdx.x;

    if (blockIdx.x < 54) {
        float* Wl = (float*)pm;                        // [128 k][17]
        const int kc6   = blockIdx.x / 9;              // phase 0..5
        const int g16   = blockIdx.x % 9;              // s-group of 16
        const int sbase = g16 * 16;
        const int scv   = (SS - sbase < 16) ? (SS - sbase) : 16;
        for (int i = tid; i < 128 * 16; i += 256) {
            int r = i >> 4, c = i & 15;
            float v = 0.f;
            if (c < scv) v = W[(size_t)(kc6 * 128 + r) * SS + sbase + c];
            Wl[r * 17 + c] = v;
        }
        __syncthreads();
        for (int i = tid; i < 16 * 64; i += 256) {     // coalesced 256B-row writes
            int sl = i >> 6, qu = i & 63;
            int s  = sbase + sl;
            int qp = qu >> 2, m = qu & 3;
            int j  = qp ^ (s & 15);                    // logical 16B slot (involution)
            int kp = j * 4 + m;                        // k-pair 0..63 within slice
            unsigned v = 0;
            if (sl < scv)
                v = f2bf(Wl[(2 * kp) * 17 + sl]) | (f2bf(Wl[(2 * kp + 1) * 17 + sl]) << 16);
            wsT2[kc6 * SLU + s * 64 + qu] = v;
        }
    } else {
        int* segl = (int*)pm;
        int* st_s = segl + 256;
        int* cn_s = segl + 512;
        const int b = blockIdx.x - 54;
        segl[tid] = seg[b * TT + tid];
        st_s[tid] = 0;
        cn_s[tid] = 0;
        __syncthreads();
        int id = segl[tid];
        if (tid == 0 || segl[tid - 1] != id) {         // run starts (seg row-sorted)
            int e = tid;
            while (e + 1 < TT && segl[e + 1] == id) ++e;
            st_s[id] = tid;
            cn_s[id] = e - tid + 1;
        }
        __syncthreads();
        bounds[b * TT + tid] = make_int2(st_s[tid], cn_s[tid]);
    }
}

// ---- K1: 6-phase DOUBLE-buffered GEMM. DMA(P+1 -> buf^1) issued at phase top,
// collected by the phase-ending __syncthreads (vmcnt drain) after ~36 MFMA of
// cover. One sync point per phase; no exposed DMA latency. 73.7 KB -> 2 blk/CU. ----
__global__ __launch_bounds__(256, 2)
void gemm_kernel(const float* __restrict__ hidden, const unsigned* __restrict__ wsT2,
                 const float* __restrict__ bias, unsigned short* __restrict__ logits)
{
    __shared__ __align__(16) unsigned Blds[2 * SLU];   // 73728 B

    const int tid  = threadIdx.x;
    const int wv   = tid >> 6;
    const int lane = tid & 63;
    const int r16  = lane & 15;
    const int g    = lane >> 4;
    const int b    = blockIdx.x >> 2;
    const int tb   = (blockIdx.x & 3) << 6;
    const float* Abase = hidden + (size_t)b * (TT + 1) * HH
                       + (size_t)(1 + tb + wv * 16 + r16) * HH + g * 8;

    f32x4 acc[9];
    #pragma unroll
    for (int j = 0; j < 9; ++j) acc[j] = (f32x4){0.f, 0.f, 0.f, 0.f};

#define DMA9(P, BUF)                                                                      \
    do {                                                                                  \
        const unsigned* gs_ = wsT2 + (size_t)(P) * SLU + wv * 2304 + lane * 4;            \
        unsigned* ld_ = Blds + (BUF) * SLU + wv * 2304;                                   \
        _Pragma("unroll")                                                                 \
        for (int i_ = 0; i_ < 9; ++i_)                                                    \
            __builtin_amdgcn_global_load_lds(gs_ + i_ * 256, ld_ + i_ * 256, 16, 0, 0);   \
    } while (0)

#define LOADA(X0, X1, X2, X3, X4, X5, X6, X7, P)                                          \
    do {                                                                                  \
        const float* ap_ = Abase + (P) * 128;                                             \
        X0 = *(const float4*)(ap_);        X1 = *(const float4*)(ap_ + 4);                \
        X2 = *(const float4*)(ap_ + 32);   X3 = *(const float4*)(ap_ + 36);               \
        X4 = *(const float4*)(ap_ + 64);   X5 = *(const float4*)(ap_ + 68);               \
        X6 = *(const float4*)(ap_ + 96);   X7 = *(const float4*)(ap_ + 100);              \
    } while (0)

#define CHUNKC(Ea, Eb, C_, BUF)                                                           \
    do {                                                                                  \
        union { unsigned u[4]; bf16x8 v; } af_;                                           \
        asm("v_cvt_pk_bf16_f32 %0, %1, %2" : "=v"(af_.u[0]) : "v"(Ea.x), "v"(Ea.y));      \
        asm("v_cvt_pk_bf16_f32 %0, %1, %2" : "=v"(af_.u[1]) : "v"(Ea.z), "v"(Ea.w));      \
        asm("v_cvt_pk_bf16_f32 %0, %1, %2" : "=v"(af_.u[2]) : "v"(Eb.x), "v"(Eb.y));      \
        asm("v_cvt_pk_bf16_f32 %0, %1, %2" : "=v"(af_.u[3]) : "v"(Eb.z), "v"(Eb.w));      \
        const char* bp_ = (const char*)Blds + (BUF) * 36864 + r16 * 256                   \
                        + ((((C_) * 4 + g) ^ r16) << 4);                                  \
        _Pragma("unroll")                                                                 \
        for (int nt = 0; nt < 9; ++nt)                                                    \
            acc[nt] = __builtin_amdgcn_mfma_f32_16x16x32_bf16(                            \
                af_.v, *(const bf16x8*)(bp_ + nt * 4096), acc[nt], 0, 0, 0);              \
    } while (0)

// phase P (buffer P&1 ready on entry): issue DMA(P+1)->buf^1, prefetch A(P+1),
// compute 4 chunks from buf, then ONE __syncthreads (drains DMA+A, barrier).
#define PHASE(C0, C1, C2, C3, C4, C5, C6, C7, N0, N1, N2, N3, N4, N5, N6, N7, P, BUF)     \
    do {                                                                                  \
        { const int pn_ = ((P) + 1 < NPH) ? (P) + 1 : NPH - 1;                            \
          DMA9(pn_, (BUF) ^ 1);                                                           \
          LOADA(N0, N1, N2, N3, N4, N5, N6, N7, pn_); }                                   \
        CHUNKC(C0, C1, 0, BUF); CHUNKC(C2, C3, 1, BUF);                                   \
        CHUNKC(C4, C5, 2, BUF); CHUNKC(C6, C7, 3, BUF);                                   \
        __syncthreads();                                                                  \
    } while (0)

    float4 e0, e1, e2, e3, e4, e5, e6, e7;
    float4 o0, o1, o2, o3, o4, o5, o6, o7;
    // prologue: B_0 -> buf0, A_0 regs; sync drains both
    DMA9(0, 0);
    LOADA(e0, e1, e2, e3, e4, e5, e6, e7, 0);
    __syncthreads();

    #pragma unroll 1
    for (int pp = 0; pp < 3; ++pp) {
        PHASE(e0, e1, e2, e3, e4, e5, e6, e7, o0, o1, o2, o3, o4, o5, o6, o7, 2 * pp, 0);
        PHASE(o0, o1, o2, o3, o4, o5, o6, o7, e0, e1, e2, e3, e4, e5, e6, e7, 2 * pp + 1, 1);
    }
#undef PHASE
#undef CHUNKC
#undef LOADA
#undef DMA9

    // epilogue: +bias, bf16 store [b][s][t], t-contiguous ushort4 per lane
    const int tq = tb + wv * 16 + g * 4;               // D row = g*4 + i
    #pragma unroll
    for (int nt = 0; nt < 9; ++nt) {
        int s = nt * 16 + r16;                          // D col = r16
        if (s < SS) {
            float bs = bias[s];
            ushort4 v;
            v.x = (unsigned short)f2bf(acc[nt][0] + bs);
            v.y = (unsigned short)f2bf(acc[nt][1] + bs);
            v.z = (unsigned short)f2bf(acc[nt][2] + bs);
            v.w = (unsigned short)f2bf(acc[nt][3] + bs);
            *(ushort4*)(logits + ((size_t)b * SS + s) * TT + tq) = v;
        }
    }
}

// ---- K2: barrier-free ragged segment-mean; 10 s-rows per block ----
__global__ __launch_bounds__(256)
void merge_kernel(const int2* __restrict__ bounds,
                  const unsigned short* __restrict__ logits,
                  float* __restrict__ out)
{
    const int blk = blockIdx.x;          // 256 * 13
    const int b   = blk / 13;
    const int sp  = (blk - b * 13) * MSP;
    const int w   = threadIdx.x;

    const int2 bc = bounds[b * TT + w];  // {start, count}
    float* obase = out + ((size_t)b * SS + sp) * TT + w;

    if (bc.y <= 0) {                     // empty word: zeros, no logits touched
        #pragma unroll
        for (int i = 0; i < MSP; ++i) obase[(size_t)i * TT] = 0.f;
        return;
    }
    const float inv = 1.f / (float)bc.y;
    const unsigned short* rbase = logits + ((size_t)b * SS + sp) * TT + bc.x;

    #pragma unroll
    for (int i = 0; i < MSP; ++i) {      // sp+i < 130 always (130 = 13*10)
        const unsigned short* row = rbase + (size_t)i * TT;
        float a = 0.f;
        for (int k = 0; k < bc.y; ++k) a += bf2f(row[k]);
        obase[(size_t)i * TT] = a * inv;
    }
}

extern "C" void kernel_launch(void* const* d_in, const int* in_sizes, int n_in,
                              void* d_out, int out_size, void* d_ws, size_t ws_size,
                              hipStream_t stream)
{
    const float* hidden = (const float*)d_in[0];  // [256, 257, 768] f32
    const float* W      = (const float*)d_in[1];  // [768, 130] f32
    const float* bias   = (const float*)d_in[2];  // [130] f32
    const int*   seg    = (const int*)d_in[3];    // [256, 256] i32 (row-sorted)
    float* out = (float*)d_out;                   // [256, 130, 256] f32

    unsigned*       wsT2   = (unsigned*)d_ws;                        // 221184 B
    int2*           bounds = (int2*)((char*)d_ws + 221184);          // 524288 B
    unsigned short* logits = (unsigned short*)((char*)d_ws + 221184 + 524288);  // 17039360 B

    (void)in_sizes; (void)n_in; (void)ws_size; (void)out_size;

    prep_kernel<<<dim3(310), dim3(256), 0, stream>>>(W, wsT2, seg, bounds);
    gemm_kernel<<<dim3(BB * 4), dim3(256), 0, stream>>>(hidden, wsT2, bias, logits);
    merge_kernel<<<dim3(BB * 13), dim3(256), 0, stream>>>(bounds, logits, out);
}

// Round 16
// 60.680 us; speedup vs baseline: 1.3992x; 1.3992x over previous
//
#include <hip/hip_runtime.h>

// Problem constants: B=256, T=256, H=768, S=130
#define BB 256
#define TT 256
#define HH 768
#define SS 130
#define NPH 6                    // K phases of 128
#define SROWS 144                // 9 n-tiles x 16 rows per B slice
#define SLU (SROWS * 64)         // uints per wsT2 phase slice = 9216 (36864 B)

typedef __attribute__((ext_vector_type(8))) __bf16 bf16x8;
typedef __attribute__((ext_vector_type(4))) float f32x4;

__device__ __forceinline__ unsigned f2bf(float f) {
    unsigned x = __builtin_bit_cast(unsigned, f);
    x = (x + 0x7FFFu + ((x >> 16) & 1u)) >> 16;
    return x & 0xFFFFu;
}
__device__ __forceinline__ float4 f4add(float4 a, float4 b) {
    return make_float4(a.x + b.x, a.y + b.y, a.z + b.z, a.w + b.w);
}

// ---- prep: [0..53] W -> wsT2 [6][144 s][128 k bf16], 16B-slot j at j^(s&15);
//            [54..309] seg -> bounds {start,count} ----
__global__ __launch_bounds__(256)
void prep_kernel(const float* __restrict__ W, unsigned* __restrict__ wsT2,
                 const int* __restrict__ seg, int2* __restrict__ bounds)
{
    __shared__ __align__(16) char pm[128 * 17 * 4];   // 8704 B
    const int tid = threadIdx.x;

    if (blockIdx.x < 54) {
        float* Wl = (float*)pm;                        // [128 k][17]
        const int kc6   = blockIdx.x / 9;              // phase 0..5
        const int g16   = blockIdx.x % 9;              // s-group of 16
        const int sbase = g16 * 16;
        const int scv   = (SS - sbase < 16) ? (SS - sbase) : 16;
        for (int i = tid; i < 128 * 16; i += 256) {
            int r = i >> 4, c = i & 15;
            float v = 0.f;
            if (c < scv) v = W[(size_t)(kc6 * 128 + r) * SS + sbase + c];
            Wl[r * 17 + c] = v;
        }
        __syncthreads();
        for (int i = tid; i < 16 * 64; i += 256) {     // coalesced 256B-row writes
            int sl = i >> 6, qu = i & 63;
            int s  = sbase + sl;
            int qp = qu >> 2, m = qu & 3;
            int j  = qp ^ (s & 15);                    // logical 16B slot (involution)
            int kp = j * 4 + m;                        // k-pair 0..63 within slice
            unsigned v = 0;
            if (sl < scv)
                v = f2bf(Wl[(2 * kp) * 17 + sl]) | (f2bf(Wl[(2 * kp + 1) * 17 + sl]) << 16);
            wsT2[kc6 * SLU + s * 64 + qu] = v;
        }
    } else {
        int* segl = (int*)pm;
        int* st_s = segl + 256;
        int* cn_s = segl + 512;
        const int b = blockIdx.x - 54;
        segl[tid] = seg[b * TT + tid];
        st_s[tid] = 0;
        cn_s[tid] = 0;
        __syncthreads();
        int id = segl[tid];
        if (tid == 0 || segl[tid - 1] != id) {         // run starts (seg row-sorted)
            int e = tid;
            while (e + 1 < TT && segl[e + 1] == id) ++e;
            st_s[id] = tid;
            cn_s[id] = e - tid + 1;
        }
        __syncthreads();
        bounds[b * TT + tid] = make_int2(st_s[tid], cn_s[tid]);
    }
}

// ---- fused: word-mean GEMM. A row = SUM of hidden rows in word's run (f32),
// epilogue scales by 1/cnt (+bias, gated) and writes d_out directly.
// out[b][s][w] = (cnt_w>0) ? (mean_t h[b,1+t,:])·W[:,s] + bias[s] : 0 ----
__global__ __launch_bounds__(256, 4)
void fused_kernel(const float* __restrict__ hidden, const unsigned* __restrict__ wsT2,
                  const float* __restrict__ bias, const int2* __restrict__ bounds,
                  float* __restrict__ out)
{
    __shared__ __align__(16) unsigned Blds[SLU];       // 36864 B -> 4 blocks/CU

    const int tid  = threadIdx.x;
    const int wv   = tid >> 6;
    const int lane = tid & 63;
    const int r16  = lane & 15;
    const int g    = lane >> 4;
    const int b    = blockIdx.x >> 2;
    const int wb   = (blockIdx.x & 3) << 6;            // 64-word span

    // this lane's A-row word and its run
    const int2 bc = bounds[b * TT + (wb + wv * 16 + r16)];
    const float* rowp = hidden + (size_t)b * (TT + 1) * HH
                      + (size_t)(1 + bc.x) * HH + g * 8;

    f32x4 acc[9];
    #pragma unroll
    for (int j = 0; j < 9; ++j) acc[j] = (f32x4){0.f, 0.f, 0.f, 0.f};

#define CHUNKC(Ea, Eb, C_)                                                                \
    do {                                                                                  \
        union { unsigned u[4]; bf16x8 v; } af_;                                           \
        asm("v_cvt_pk_bf16_f32 %0, %1, %2" : "=v"(af_.u[0]) : "v"(Ea.x), "v"(Ea.y));      \
        asm("v_cvt_pk_bf16_f32 %0, %1, %2" : "=v"(af_.u[1]) : "v"(Ea.z), "v"(Ea.w));      \
        asm("v_cvt_pk_bf16_f32 %0, %1, %2" : "=v"(af_.u[2]) : "v"(Eb.x), "v"(Eb.y));      \
        asm("v_cvt_pk_bf16_f32 %0, %1, %2" : "=v"(af_.u[3]) : "v"(Eb.z), "v"(Eb.w));      \
        const char* bp_ = (const char*)Blds + r16 * 256 + ((((C_) * 4 + g) ^ r16) << 4);  \
        _Pragma("unroll")                                                                 \
        for (int nt = 0; nt < 9; ++nt)                                                    \
            acc[nt] = __builtin_amdgcn_mfma_f32_16x16x32_bf16(                            \
                af_.v, *(const bf16x8*)(bp_ + nt * 4096), acc[nt], 0, 0, 0);              \
    } while (0)

    #pragma unroll 1
    for (int P = 0; P < NPH; ++P) {
        __syncthreads();                               // buf free (prev phase done)
        {   // B slice P -> LDS (linear dest, pre-swizzled source)
            const unsigned* gs_ = wsT2 + (size_t)P * SLU + wv * 2304 + lane * 4;
            unsigned* ld_ = Blds + wv * 2304;
            #pragma unroll
            for (int i_ = 0; i_ < 9; ++i_)
                __builtin_amdgcn_global_load_lds(gs_ + i_ * 256, ld_ + i_ * 256, 16, 0, 0);
        }
        asm volatile("s_waitcnt vmcnt(0)" ::: "memory");
        __syncthreads();

        // A: summed word-row slice for this phase (f32)
        float4 s0 = {0,0,0,0}, s1 = {0,0,0,0}, s2 = {0,0,0,0}, s3 = {0,0,0,0};
        float4 s4 = {0,0,0,0}, s5 = {0,0,0,0}, s6 = {0,0,0,0}, s7 = {0,0,0,0};
        if (bc.y > 0) {
            const float* p_ = rowp + P * 128;
            s0 = *(const float4*)(p_);       s1 = *(const float4*)(p_ + 4);
            s2 = *(const float4*)(p_ + 32);  s3 = *(const float4*)(p_ + 36);
            s4 = *(const float4*)(p_ + 64);  s5 = *(const float4*)(p_ + 68);
            s6 = *(const float4*)(p_ + 96);  s7 = *(const float4*)(p_ + 100);
            for (int k = 1; k < bc.y; ++k) {
                const float* q_ = p_ + (size_t)k * HH;
                float4 t0 = *(const float4*)(q_);       float4 t1 = *(const float4*)(q_ + 4);
                float4 t2 = *(const float4*)(q_ + 32);  float4 t3 = *(const float4*)(q_ + 36);
                float4 t4 = *(const float4*)(q_ + 64);  float4 t5 = *(const float4*)(q_ + 68);
                float4 t6 = *(const float4*)(q_ + 96);  float4 t7 = *(const float4*)(q_ + 100);
                s0 = f4add(s0, t0); s1 = f4add(s1, t1); s2 = f4add(s2, t2); s3 = f4add(s3, t3);
                s4 = f4add(s4, t4); s5 = f4add(s5, t5); s6 = f4add(s6, t6); s7 = f4add(s7, t7);
            }
        }
        CHUNKC(s0, s1, 0); CHUNKC(s2, s3, 1); CHUNKC(s4, s5, 2); CHUNKC(s6, s7, 3);
    }
#undef CHUNKC

    // epilogue: scale by 1/cnt, +bias (gated), write out[b][s][w] directly
    const int tq = wb + wv * 16 + g * 4;               // D row i -> word tq+i
    float inv0, inv1, inv2, inv3, gt0, gt1, gt2, gt3;
    {
        int2 q0 = bounds[b * TT + tq + 0];
        int2 q1 = bounds[b * TT + tq + 1];
        int2 q2 = bounds[b * TT + tq + 2];
        int2 q3 = bounds[b * TT + tq + 3];
        inv0 = (q0.y > 0) ? 1.f / (float)q0.y : 0.f;  gt0 = (q0.y > 0) ? 1.f : 0.f;
        inv1 = (q1.y > 0) ? 1.f / (float)q1.y : 0.f;  gt1 = (q1.y > 0) ? 1.f : 0.f;
        inv2 = (q2.y > 0) ? 1.f / (float)q2.y : 0.f;  gt2 = (q2.y > 0) ? 1.f : 0.f;
        inv3 = (q3.y > 0) ? 1.f / (float)q3.y : 0.f;  gt3 = (q3.y > 0) ? 1.f : 0.f;
    }
    #pragma unroll
    for (int nt = 0; nt < 9; ++nt) {
        int s = nt * 16 + r16;                          // D col = r16
        if (s < SS) {
            float bs = bias[s];
            float4 v;
            v.x = acc[nt][0] * inv0 + gt0 * bs;
            v.y = acc[nt][1] * inv1 + gt1 * bs;
            v.z = acc[nt][2] * inv2 + gt2 * bs;
            v.w = acc[nt][3] * inv3 + gt3 * bs;
            *(float4*)(out + ((size_t)b * SS + s) * TT + tq) = v;
        }
    }
}

extern "C" void kernel_launch(void* const* d_in, const int* in_sizes, int n_in,
                              void* d_out, int out_size, void* d_ws, size_t ws_size,
                              hipStream_t stream)
{
    const float* hidden = (const float*)d_in[0];  // [256, 257, 768] f32
    const float* W      = (const float*)d_in[1];  // [768, 130] f32
    const float* bias   = (const float*)d_in[2];  // [130] f32
    const int*   seg    = (const int*)d_in[3];    // [256, 256] i32 (row-sorted)
    float* out = (float*)d_out;                   // [256, 130, 256] f32

    unsigned* wsT2   = (unsigned*)d_ws;                      // 221184 B
    int2*     bounds = (int2*)((char*)d_ws + 221184);        // 524288 B

    (void)in_sizes; (void)n_in; (void)ws_size; (void)out_size;

    prep_kernel<<<dim3(310), dim3(256), 0, stream>>>(W, wsT2, seg, bounds);
    fused_kernel<<<dim3(BB * 4), dim3(256), 0, stream>>>(hidden, wsT2, bias, bounds, out);
}

// Round 17
// 60.632 us; speedup vs baseline: 1.4003x; 1.0008x over previous
//
#include <hip/hip_runtime.h>

// Problem constants: B=256, T=256, H=768, S=130
#define BB 256
#define TT 256
#define HH 768
#define SS 130
#define NPH 6                    // K phases of 128
#define SROWS 144                // 9 n-tiles x 16 rows per B slice
#define SLU (SROWS * 64)         // uints per wsT2 phase slice = 9216 (36864 B)

typedef __attribute__((ext_vector_type(8))) __bf16 bf16x8;
typedef __attribute__((ext_vector_type(4))) float f32x4;

__device__ __forceinline__ unsigned f2bf(float f) {
    unsigned x = __builtin_bit_cast(unsigned, f);
    x = (x + 0x7FFFu + ((x >> 16) & 1u)) >> 16;
    return x & 0xFFFFu;
}
__device__ __forceinline__ float4 f4add(float4 a, float4 b) {
    return make_float4(a.x + b.x, a.y + b.y, a.z + b.z, a.w + b.w);
}

// ---- prep (W only): W [768][130] f32 -> wsT2 [6][144 s][128 k bf16],
// 16B-slot j stored at j^(s&15) within each 256B row. 54 blocks. ----
__global__ __launch_bounds__(256)
void prep_kernel(const float* __restrict__ W, unsigned* __restrict__ wsT2)
{
    __shared__ __align__(16) float Wl[128 * 17];       // 8704 B
    const int tid = threadIdx.x;
    const int kc6   = blockIdx.x / 9;                  // phase 0..5
    const int g16   = blockIdx.x % 9;                  // s-group of 16
    const int sbase = g16 * 16;
    const int scv   = (SS - sbase < 16) ? (SS - sbase) : 16;

    for (int i = tid; i < 128 * 16; i += 256) {
        int r = i >> 4, c = i & 15;
        float v = 0.f;
        if (c < scv) v = W[(size_t)(kc6 * 128 + r) * SS + sbase + c];
        Wl[r * 17 + c] = v;
    }
    __syncthreads();
    for (int i = tid; i < 16 * 64; i += 256) {         // coalesced 256B-row writes
        int sl = i >> 6, qu = i & 63;
        int s  = sbase + sl;
        int qp = qu >> 2, m = qu & 3;
        int j  = qp ^ (s & 15);                        // logical 16B slot (involution)
        int kp = j * 4 + m;                            // k-pair 0..63 within slice
        unsigned v = 0;
        if (sl < scv)
            v = f2bf(Wl[(2 * kp) * 17 + sl]) | (f2bf(Wl[(2 * kp + 1) * 17 + sl]) << 16);
        wsT2[kc6 * SLU + s * 64 + qu] = v;
    }
}

// ---- fused: in-block seg scan + word-mean GEMM, writes d_out directly.
// out[b][s][w] = (cnt_w>0) ? (mean_{t in run(w)} h[b,1+t,:])·W[:,s] + bias[s] : 0 ----
__global__ __launch_bounds__(256, 4)
void fused_kernel(const float* __restrict__ hidden, const unsigned* __restrict__ wsT2,
                  const float* __restrict__ bias, const int* __restrict__ seg,
                  float* __restrict__ out)
{
    __shared__ __align__(16) unsigned Blds[SLU];       // 36864 B
    __shared__ int segl[TT];                           // + 3072 B -> 39936 <= 40960
    __shared__ int st_s[TT];
    __shared__ int cn_s[TT];

    const int tid  = threadIdx.x;
    const int wv   = tid >> 6;
    const int lane = tid & 63;
    const int r16  = lane & 15;
    const int g    = lane >> 4;
    const int b    = blockIdx.x >> 2;
    const int wb   = (blockIdx.x & 3) << 6;            // 64-word span

    // ---- in-block run-boundary scan (seg row-sorted -> contiguous runs) ----
    segl[tid] = seg[b * TT + tid];
    st_s[tid] = 0;
    cn_s[tid] = 0;
    __syncthreads();
    {
        int id = segl[tid];
        if (tid == 0 || segl[tid - 1] != id) {
            int e = tid;
            while (e + 1 < TT && segl[e + 1] == id) ++e;
            st_s[id] = tid;
            cn_s[id] = e - tid + 1;
        }
    }
    __syncthreads();

    // this lane's A-row word and its run
    const int mw  = wb + wv * 16 + r16;
    const int mst = st_s[mw];
    const int mcn = cn_s[mw];
    const float* rowp = hidden + (size_t)b * (TT + 1) * HH
                      + (size_t)(1 + mst) * HH + g * 8;

    f32x4 acc[9];
    #pragma unroll
    for (int j = 0; j < 9; ++j) acc[j] = (f32x4){0.f, 0.f, 0.f, 0.f};

#define CHUNKC(Ea, Eb, C_)                                                                \
    do {                                                                                  \
        union { unsigned u[4]; bf16x8 v; } af_;                                           \
        asm("v_cvt_pk_bf16_f32 %0, %1, %2" : "=v"(af_.u[0]) : "v"(Ea.x), "v"(Ea.y));      \
        asm("v_cvt_pk_bf16_f32 %0, %1, %2" : "=v"(af_.u[1]) : "v"(Ea.z), "v"(Ea.w));      \
        asm("v_cvt_pk_bf16_f32 %0, %1, %2" : "=v"(af_.u[2]) : "v"(Eb.x), "v"(Eb.y));      \
        asm("v_cvt_pk_bf16_f32 %0, %1, %2" : "=v"(af_.u[3]) : "v"(Eb.z), "v"(Eb.w));      \
        const char* bp_ = (const char*)Blds + r16 * 256 + ((((C_) * 4 + g) ^ r16) << 4);  \
        _Pragma("unroll")                                                                 \
        for (int nt = 0; nt < 9; ++nt)                                                    \
            acc[nt] = __builtin_amdgcn_mfma_f32_16x16x32_bf16(                            \
                af_.v, *(const bf16x8*)(bp_ + nt * 4096), acc[nt], 0, 0, 0);              \
    } while (0)

    #pragma unroll 1
    for (int P = 0; P < NPH; ++P) {
        __syncthreads();                               // buf free (prev phase done)
        {   // B slice P -> LDS (linear dest, pre-swizzled source)
            const unsigned* gs_ = wsT2 + (size_t)P * SLU + wv * 2304 + lane * 4;
            unsigned* ld_ = Blds + wv * 2304;
            #pragma unroll
            for (int i_ = 0; i_ < 9; ++i_)
                __builtin_amdgcn_global_load_lds(gs_ + i_ * 256, ld_ + i_ * 256, 16, 0, 0);
        }
        asm volatile("s_waitcnt vmcnt(0)" ::: "memory");
        __syncthreads();

        // A: summed word-row slice for this phase (f32)
        float4 s0 = {0,0,0,0}, s1 = {0,0,0,0}, s2 = {0,0,0,0}, s3 = {0,0,0,0};
        float4 s4 = {0,0,0,0}, s5 = {0,0,0,0}, s6 = {0,0,0,0}, s7 = {0,0,0,0};
        if (mcn > 0) {
            const float* p_ = rowp + P * 128;
            s0 = *(const float4*)(p_);       s1 = *(const float4*)(p_ + 4);
            s2 = *(const float4*)(p_ + 32);  s3 = *(const float4*)(p_ + 36);
            s4 = *(const float4*)(p_ + 64);  s5 = *(const float4*)(p_ + 68);
            s6 = *(const float4*)(p_ + 96);  s7 = *(const float4*)(p_ + 100);
            for (int k = 1; k < mcn; ++k) {
                const float* q_ = p_ + (size_t)k * HH;
                float4 t0 = *(const float4*)(q_);       float4 t1 = *(const float4*)(q_ + 4);
                float4 t2 = *(const float4*)(q_ + 32);  float4 t3 = *(const float4*)(q_ + 36);
                float4 t4 = *(const float4*)(q_ + 64);  float4 t5 = *(const float4*)(q_ + 68);
                float4 t6 = *(const float4*)(q_ + 96);  float4 t7 = *(const float4*)(q_ + 100);
                s0 = f4add(s0, t0); s1 = f4add(s1, t1); s2 = f4add(s2, t2); s3 = f4add(s3, t3);
                s4 = f4add(s4, t4); s5 = f4add(s5, t5); s6 = f4add(s6, t6); s7 = f4add(s7, t7);
            }
        }
        CHUNKC(s0, s1, 0); CHUNKC(s2, s3, 1); CHUNKC(s4, s5, 2); CHUNKC(s6, s7, 3);
    }
#undef CHUNKC

    // epilogue: scale by 1/cnt, +bias (gated), write out[b][s][w] directly
    const int tq = wb + wv * 16 + g * 4;               // D row i -> word tq+i
    const int c0 = cn_s[tq + 0], c1 = cn_s[tq + 1];
    const int c2 = cn_s[tq + 2], c3 = cn_s[tq + 3];
    const float inv0 = (c0 > 0) ? 1.f / (float)c0 : 0.f, gt0 = (c0 > 0) ? 1.f : 0.f;
    const float inv1 = (c1 > 0) ? 1.f / (float)c1 : 0.f, gt1 = (c1 > 0) ? 1.f : 0.f;
    const float inv2 = (c2 > 0) ? 1.f / (float)c2 : 0.f, gt2 = (c2 > 0) ? 1.f : 0.f;
    const float inv3 = (c3 > 0) ? 1.f / (float)c3 : 0.f, gt3 = (c3 > 0) ? 1.f : 0.f;

    #pragma unroll
    for (int nt = 0; nt < 9; ++nt) {
        int s = nt * 16 + r16;                          // D col = r16
        if (s < SS) {
            float bs = bias[s];
            float4 v;
            v.x = acc[nt][0] * inv0 + gt0 * bs;
            v.y = acc[nt][1] * inv1 + gt1 * bs;
            v.z = acc[nt][2] * inv2 + gt2 * bs;
            v.w = acc[nt][3] * inv3 + gt3 * bs;
            *(float4*)(out + ((size_t)b * SS + s) * TT + tq) = v;
        }
    }
}

extern "C" void kernel_launch(void* const* d_in, const int* in_sizes, int n_in,
                              void* d_out, int out_size, void* d_ws, size_t ws_size,
                              hipStream_t stream)
{
    const float* hidden = (const float*)d_in[0];  // [256, 257, 768] f32
    const float* W      = (const float*)d_in[1];  // [768, 130] f32
    const float* bias   = (const float*)d_in[2];  // [130] f32
    const int*   seg    = (const int*)d_in[3];    // [256, 256] i32 (row-sorted)
    float* out = (float*)d_out;                   // [256, 130, 256] f32

    unsigned* wsT2 = (unsigned*)d_ws;             // 221184 B

    (void)in_sizes; (void)n_in; (void)ws_size; (void)out_size;

    prep_kernel<<<dim3(54), dim3(256), 0, stream>>>(W, wsT2);
    fused_kernel<<<dim3(BB * 4), dim3(256), 0, stream>>>(hidden, wsT2, bias, seg, out);
}